// Round 15
// baseline (323.220 us; speedup 1.0000x reference)
//
#include <hip/hip_runtime.h>
#include <hip/hip_fp16.h>

typedef _Float16 v2h __attribute__((ext_vector_type(2)));
typedef _Float16 h4t __attribute__((ext_vector_type(4)));
typedef float f4t __attribute__((ext_vector_type(4)));

static constexpr int T = 512;
static constexpr int B = 4096;

// prescale constants: sigmoid gates get -log2e, tanh gates get -2*log2e
static constexpr float SG = -1.4426950408889634f;
static constexpr float SN = -2.8853900817779268f;

__device__ __forceinline__ float frcp_(float x) { return __builtin_amdgcn_rcpf(x); }
__device__ __forceinline__ float exp2_(float x) {
#if __has_builtin(__builtin_amdgcn_exp2f)
    return __builtin_amdgcn_exp2f(x);
#else
    return __expf(x * 0.69314718055994531f);
#endif
}
__device__ __forceinline__ float sigp_(float p) { return frcp_(1.0f + exp2_(p)); }
__device__ __forceinline__ float tanhp_(float p) { return fmaf(2.0f, frcp_(1.0f + exp2_(p)), -1.0f); }

#define WAVE_SYNC() do { asm volatile("" ::: "memory"); \
                         __builtin_amdgcn_wave_barrier(); \
                         asm volatile("" ::: "memory"); } while (0)

__device__ __forceinline__ v2h as_h2_(unsigned u) {
    union { unsigned u; v2h h; } c; c.u = u; return c.h;
}
__device__ __forceinline__ h4t as_h4_(uint2 u) {
    union { uint2 u; h4t h; } c; c.u = u; return c.h;
}

// pack 4 floats -> h4t via two v_cvt_pkrtz
__device__ __forceinline__ h4t pack4_(float a, float b, float c, float d) {
    auto p0 = __builtin_amdgcn_cvt_pkrtz(a, b);
    auto p1 = __builtin_amdgcn_cvt_pkrtz(c, d);
    union { struct { decltype(p0) a, b; } p; h4t h; } cv;
    cv.p.a = p0; cv.p.b = p1;
    return cv.h;
}

// ---------------- Kernel 1: layer-0 BACKWARD scan only ---------------------
// r14 k_l0 structure with dir fixed to backward; 16 units of 16 lanes per
// block, 256 blocks (1024 waves). Writes y0b [T,B,16] f16.
__global__ void __launch_bounds__(256, 2) k_l0b(
    const float* __restrict__ x,      // [B,T]
    const float* __restrict__ Wb, const float* __restrict__ Ub,
    const float* __restrict__ bib, const float* __restrict__ bhb,
    __half* __restrict__ y0b)         // [T,B,16] f16
{
    __shared__ __half hbuf[256];
    const int tid  = threadIdx.x;
    const int j    = tid & 15;
    const int unit = tid >> 4;
    const int b    = blockIdx.x * 16 + unit;
    __half* hb = hbuf + unit * 16;

    v2h wr[8], wz[8], wn[8];
#pragma unroll
    for (int q = 0; q < 8; ++q) {
        wr[q] = (v2h){ (_Float16)(SG * Ub[j * 16 + 2 * q]),
                       (_Float16)(SG * Ub[j * 16 + 2 * q + 1]) };
        wz[q] = (v2h){ (_Float16)(SG * Ub[(16 + j) * 16 + 2 * q]),
                       (_Float16)(SG * Ub[(16 + j) * 16 + 2 * q + 1]) };
        wn[q] = (v2h){ (_Float16)(SN * Ub[(32 + j) * 16 + 2 * q]),
                       (_Float16)(SN * Ub[(32 + j) * 16 + 2 * q + 1]) };
    }
    const float wxr  = SG * Wb[j], wxz = SG * Wb[16 + j], wxn = SN * Wb[32 + j];
    const float br   = SG * (bib[j] + bhb[j]);
    const float bz   = SG * (bib[16 + j] + bhb[16 + j]);
    const float bin_ = SN * bib[32 + j];
    const float bhn  = SN * bhb[32 + j];

    const float* xp = x + (size_t)b * T + (T - 1);
    __half* yp = y0b + ((size_t)(T - 1) * B + b) * 16 + j;

    hb[j] = __half(0.0f);
    WAVE_SYNC();

    float xv = xp[0];
    float x1 = xp[-1];
    const float* xq = xp - 2;
    float hj = 0.0f;

    for (int it = 0; it < T; ++it) {
        float x2 = *xq;
        if (it < T - 3) xq -= 1;
        const uint4* hp = reinterpret_cast<const uint4*>(hb);
        uint4 u0 = hp[0], u1 = hp[1];
        float ar = fmaf(xv, wxr, br);
        float az = fmaf(xv, wxz, bz);
        float hn = bhn;
        const unsigned hw[8] = { u0.x, u0.y, u0.z, u0.w, u1.x, u1.y, u1.z, u1.w };
#pragma unroll
        for (int q = 0; q < 8; ++q) {
            v2h hh = as_h2_(hw[q]);
            ar = __builtin_amdgcn_fdot2(hh, wr[q], ar, false);
            az = __builtin_amdgcn_fdot2(hh, wz[q], az, false);
            hn = __builtin_amdgcn_fdot2(hh, wn[q], hn, false);
        }
        float r = sigp_(ar), z = sigp_(az);
        float n = tanhp_(fmaf(r, hn, fmaf(xv, wxn, bin_)));
        hj = fmaf(z, hj - n, n);
        __half hf = __float2half(hj);
        *yp = hf;
        yp -= (ptrdiff_t)B * 16;
        WAVE_SYNC();
        hb[j] = hf;
        WAVE_SYNC();
        xv = x1; x1 = x2;
    }
}

// -------- Kernel 2: fused L0-fwd + L1-fwd (skewed) + L1-bwd, MFMA ----------
// 16 seqs/wave, 256 waves. L0-fwd: 3x mfma_16x16x16f16 (x in C), h0 stays
// in registers (D->B identity, r9-verified). L1 runs one step behind:
// ih = chained K=16 MFMAs over [Bh0_prev | y0b-prefetch], hh C-chained.
// All gate weights exp2-prescaled.
__global__ void __launch_bounds__(64, 1) k_fused(
    const float* __restrict__ x,
    const float* __restrict__ Wih0, const float* __restrict__ Whh0,
    const float* __restrict__ bih0, const float* __restrict__ bhh0,
    const float* __restrict__ Wih1, const float* __restrict__ Whh1,
    const float* __restrict__ bih1, const float* __restrict__ bhh1,
    const float* __restrict__ Wih1b,
    const float* __restrict__ bih1b, const float* __restrict__ bhh1b,
    const __half* __restrict__ y0b,   // [T,B,16] f16
    float* __restrict__ out)          // [B,32]
{
    const int lane = threadIdx.x & 63;
    const int c = lane & 15;
    const int g = lane >> 4;
    const int b = blockIdx.x * 16 + c;

    // ---- L0-fwd hh fragments (K=16): A[m=c][k=4g+e], prescaled
    h4t A0r, A0z, A0n;
#pragma unroll
    for (int e = 0; e < 4; ++e) {
        A0r[e] = (_Float16)(SG * Whh0[(size_t)c * 16 + 4 * g + e]);
        A0z[e] = (_Float16)(SG * Whh0[(size_t)(16 + c) * 16 + 4 * g + e]);
        A0n[e] = (_Float16)(SN * Whh0[(size_t)(32 + c) * 16 + 4 * g + e]);
    }
    float sgwxr[4], sgwxz[4], snwxn[4], br0[4], bz0[4], bn0[4];
    f4t Chn0;
#pragma unroll
    for (int i = 0; i < 4; ++i) {
        const int row = 4 * g + i;
        sgwxr[i] = SG * Wih0[row];
        sgwxz[i] = SG * Wih0[16 + row];
        snwxn[i] = SN * Wih0[32 + row];
        br0[i] = SG * (bih0[row] + bhh0[row]);
        bz0[i] = SG * (bih0[16 + row] + bhh0[16 + row]);
        bn0[i] = SN * bih0[32 + row];
        Chn0[i] = SN * bhh0[32 + row];
    }

    // ---- L1 fragments: ih split into h0-part / y-part (each K=16)
    h4t P0r, P0z, P0n, Pyr, Pyz, Pyn, U1r, U1z, U1n;
#pragma unroll
    for (int e = 0; e < 4; ++e) {
        const int k = 4 * g + e;
        P0r[e] = (_Float16)(SG * Wih1[(size_t)c * 32 + k]);
        P0z[e] = (_Float16)(SG * Wih1[(size_t)(16 + c) * 32 + k]);
        P0n[e] = (_Float16)(SN * Wih1[(size_t)(32 + c) * 32 + k]);
        Pyr[e] = (_Float16)(SG * Wih1[(size_t)c * 32 + 16 + k]);
        Pyz[e] = (_Float16)(SG * Wih1[(size_t)(16 + c) * 32 + 16 + k]);
        Pyn[e] = (_Float16)(SN * Wih1[(size_t)(32 + c) * 32 + 16 + k]);
        U1r[e] = (_Float16)(SG * Whh1[(size_t)c * 16 + k]);
        U1z[e] = (_Float16)(SG * Whh1[(size_t)(16 + c) * 16 + k]);
        U1n[e] = (_Float16)(SN * Whh1[(size_t)(32 + c) * 16 + k]);
    }
    f4t Crb, Czb, Cnb, Chn1;
#pragma unroll
    for (int i = 0; i < 4; ++i) {
        const int row = 4 * g + i;
        Crb[i] = SG * (bih1[row] + bhh1[row]);
        Czb[i] = SG * (bih1[16 + row] + bhh1[16 + row]);
        Cnb[i] = SN * bih1[32 + row];
        Chn1[i] = SN * bhh1[32 + row];
    }

    // ---- y0b prefetch: lane needs y0b[t][b][4g..4g+3] = 8 B
    const uint2* yq = reinterpret_cast<const uint2*>(y0b) + (size_t)b * 4 + g;
    const size_t ystr = (size_t)B * 4;             // uint2 per time step
    // buf[u] at iter it (u=it&3) holds y(max(it-1,0))
    uint2 buf[4];
    buf[0] = yq[0];
    buf[1] = yq[0];
    buf[2] = yq[ystr];
    buf[3] = yq[2 * ystr];

    const float* xp = x + (size_t)b * T;
    float x_cur = xp[0];
    float x_nxt = xp[1];
    const float* xq2 = xp + 2;

    float h0[4] = {0.0f, 0.0f, 0.0f, 0.0f};
    float h1[4] = {0.0f, 0.0f, 0.0f, 0.0f};
    h4t Bh0 = {}, Bh1 = {};

    for (int ito = 0; ito < T / 4; ++ito) {
#pragma unroll
        for (int u = 0; u < 4; ++u) {
            const int it = ito * 4 + u;
            uint2 yau = buf[u];
            const size_t tn = (it + 3 < T) ? (size_t)(it + 3) : (size_t)(T - 1);
            buf[u] = yq[tn * ystr];
            float x2 = *xq2;
            if (it < T - 3) xq2 += 1;

            // ---- L0-fwd MFMAs (step it, uses Bh0 = h0(it-1))
            f4t C0r, C0z;
            float inx[4];
#pragma unroll
            for (int i = 0; i < 4; ++i) {
                C0r[i] = fmaf(x_cur, sgwxr[i], br0[i]);
                C0z[i] = fmaf(x_cur, sgwxz[i], bz0[i]);
                inx[i] = fmaf(x_cur, snwxn[i], bn0[i]);
            }
            f4t E0r = __builtin_amdgcn_mfma_f32_16x16x16f16(A0r, Bh0, C0r, 0, 0, 0);
            f4t E0z = __builtin_amdgcn_mfma_f32_16x16x16f16(A0z, Bh0, C0z, 0, 0, 0);
            f4t E0n = __builtin_amdgcn_mfma_f32_16x16x16f16(A0n, Bh0, Chn0, 0, 0, 0);

            // ---- L1 MFMAs (step it-1: Bh0 = h0(it-1), yau = y(it-1), Bh1 = h1(it-2))
            h4t By = as_h4_(yau);
            f4t D1r = __builtin_amdgcn_mfma_f32_16x16x16f16(P0r, Bh0, Crb, 0, 0, 0);
            f4t D1z = __builtin_amdgcn_mfma_f32_16x16x16f16(P0z, Bh0, Czb, 0, 0, 0);
            f4t D1n = __builtin_amdgcn_mfma_f32_16x16x16f16(P0n, Bh0, Cnb, 0, 0, 0);
            D1r = __builtin_amdgcn_mfma_f32_16x16x16f16(Pyr, By, D1r, 0, 0, 0);
            D1z = __builtin_amdgcn_mfma_f32_16x16x16f16(Pyz, By, D1z, 0, 0, 0);
            D1n = __builtin_amdgcn_mfma_f32_16x16x16f16(Pyn, By, D1n, 0, 0, 0);
            f4t E1r = __builtin_amdgcn_mfma_f32_16x16x16f16(U1r, Bh1, D1r, 0, 0, 0);
            f4t E1z = __builtin_amdgcn_mfma_f32_16x16x16f16(U1z, Bh1, D1z, 0, 0, 0);
            f4t E1n = __builtin_amdgcn_mfma_f32_16x16x16f16(U1n, Bh1, Chn1, 0, 0, 0);

            // ---- L0 nonlinearity
#pragma unroll
            for (int i = 0; i < 4; ++i) {
                float r = sigp_(E0r[i]);
                float z = sigp_(E0z[i]);
                float n = tanhp_(fmaf(r, E0n[i], inx[i]));
                h0[i] = fmaf(z, h0[i] - n, n);
            }
            // ---- L1 nonlinearity (discard warm-up at it=0: h1(-1)=0)
#pragma unroll
            for (int i = 0; i < 4; ++i) {
                float r = sigp_(E1r[i]);
                float z = sigp_(E1z[i]);
                float n = tanhp_(fmaf(r, E1n[i], D1n[i]));
                float hv = fmaf(z, h1[i] - n, n);
                h1[i] = (it == 0) ? 0.0f : hv;
            }
            Bh0 = pack4_(h0[0], h0[1], h0[2], h0[3]);
            Bh1 = pack4_(h1[0], h1[1], h1[2], h1[3]);
            x_cur = x_nxt; x_nxt = x2;
        }
    }

    // ---- final L1 step (t = T-1): Bh0 = h0(T-1), Bh1 = h1(T-2), y(T-1)
    h4t Byf = as_h4_(buf[(T - 1) & 3]);
    {
        f4t D1r = __builtin_amdgcn_mfma_f32_16x16x16f16(P0r, Bh0, Crb, 0, 0, 0);
        f4t D1z = __builtin_amdgcn_mfma_f32_16x16x16f16(P0z, Bh0, Czb, 0, 0, 0);
        f4t D1n = __builtin_amdgcn_mfma_f32_16x16x16f16(P0n, Bh0, Cnb, 0, 0, 0);
        D1r = __builtin_amdgcn_mfma_f32_16x16x16f16(Pyr, Byf, D1r, 0, 0, 0);
        D1z = __builtin_amdgcn_mfma_f32_16x16x16f16(Pyz, Byf, D1z, 0, 0, 0);
        D1n = __builtin_amdgcn_mfma_f32_16x16x16f16(Pyn, Byf, D1n, 0, 0, 0);
        f4t E1r = __builtin_amdgcn_mfma_f32_16x16x16f16(U1r, Bh1, D1r, 0, 0, 0);
        f4t E1z = __builtin_amdgcn_mfma_f32_16x16x16f16(U1z, Bh1, D1z, 0, 0, 0);
        f4t E1n = __builtin_amdgcn_mfma_f32_16x16x16f16(U1n, Bh1, Chn1, 0, 0, 0);
#pragma unroll
        for (int i = 0; i < 4; ++i) {
            float r = sigp_(E1r[i]);
            float z = sigp_(E1z[i]);
            float n = tanhp_(fmaf(r, E1n[i], D1n[i]));
            h1[i] = fmaf(z, h1[i] - n, n);
            out[(size_t)b * 32 + 4 * g + i] = h1[i];
        }
    }

    // ---- L1 backward single step at t = T-1 from h=0
    h4t Qb0r, Qb0z, Qb0n, Qbyr, Qbyz, Qbyn;
#pragma unroll
    for (int e = 0; e < 4; ++e) {
        const int k = 4 * g + e;
        Qb0r[e] = (_Float16)(SG * Wih1b[(size_t)c * 32 + k]);
        Qb0z[e] = (_Float16)(SG * Wih1b[(size_t)(16 + c) * 32 + k]);
        Qb0n[e] = (_Float16)(SN * Wih1b[(size_t)(32 + c) * 32 + k]);
        Qbyr[e] = (_Float16)(SG * Wih1b[(size_t)c * 32 + 16 + k]);
        Qbyz[e] = (_Float16)(SG * Wih1b[(size_t)(16 + c) * 32 + 16 + k]);
        Qbyn[e] = (_Float16)(SN * Wih1b[(size_t)(32 + c) * 32 + 16 + k]);
    }
    f4t Cbr, Cbz, Cbn;
    float ghn[4];
#pragma unroll
    for (int i = 0; i < 4; ++i) {
        const int row = 4 * g + i;
        Cbr[i] = SG * (bih1b[row] + bhh1b[row]);
        Cbz[i] = SG * (bih1b[16 + row] + bhh1b[16 + row]);
        Cbn[i] = SN * bih1b[32 + row];
        ghn[i] = SN * bhh1b[32 + row];
    }
    f4t Gr = __builtin_amdgcn_mfma_f32_16x16x16f16(Qb0r, Bh0, Cbr, 0, 0, 0);
    f4t Gz = __builtin_amdgcn_mfma_f32_16x16x16f16(Qb0z, Bh0, Cbz, 0, 0, 0);
    f4t Gn = __builtin_amdgcn_mfma_f32_16x16x16f16(Qb0n, Bh0, Cbn, 0, 0, 0);
    Gr = __builtin_amdgcn_mfma_f32_16x16x16f16(Qbyr, Byf, Gr, 0, 0, 0);
    Gz = __builtin_amdgcn_mfma_f32_16x16x16f16(Qbyz, Byf, Gz, 0, 0, 0);
    Gn = __builtin_amdgcn_mfma_f32_16x16x16f16(Qbyn, Byf, Gn, 0, 0, 0);
#pragma unroll
    for (int i = 0; i < 4; ++i) {
        float r = sigp_(Gr[i]);
        float z = sigp_(Gz[i]);
        float n = tanhp_(fmaf(r, ghn[i], Gn[i]));
        out[(size_t)b * 32 + 16 + 4 * g + i] = (1.0f - z) * n;
    }
}

extern "C" void kernel_launch(void* const* d_in, const int* in_sizes, int n_in,
                              void* d_out, int out_size, void* d_ws, size_t ws_size,
                              hipStream_t stream) {
    const float* x     = (const float*)d_in[0];
    const float* Wih0f = (const float*)d_in[1];
    const float* Whh0f = (const float*)d_in[2];
    const float* bih0f = (const float*)d_in[3];
    const float* bhh0f = (const float*)d_in[4];
    const float* Wih0b = (const float*)d_in[5];
    const float* Whh0b = (const float*)d_in[6];
    const float* bih0b = (const float*)d_in[7];
    const float* bhh0b = (const float*)d_in[8];
    const float* Wih1f = (const float*)d_in[9];
    const float* Whh1f = (const float*)d_in[10];
    const float* bih1f = (const float*)d_in[11];
    const float* bhh1f = (const float*)d_in[12];
    const float* Wih1b = (const float*)d_in[13];
    const float* bih1b = (const float*)d_in[15];
    const float* bhh1b = (const float*)d_in[16];

    __half* y0b = (__half*)d_ws;                   // [T,B,16] f16 = 64 MiB
    float* out = (float*)d_out;

    // K1: 4096 bwd units, 16 per block -> 256 blocks.
    hipLaunchKernelGGL(k_l0b, dim3(B / 16), dim3(256), 0, stream,
                       x, Wih0b, Whh0b, bih0b, bhh0b, y0b);
    // K2: 4096 seqs, 16 per wave -> 256 blocks.
    hipLaunchKernelGGL(k_fused, dim3(B / 16), dim3(64), 0, stream,
                       x, Wih0f, Whh0f, bih0f, bhh0f,
                       Wih1f, Whh1f, bih1f, bhh1f,
                       Wih1b, bih1b, bhh1b, y0b, out);
}

// Round 16
// 306.015 us; speedup vs baseline: 1.0562x; 1.0562x over previous
//
#include <hip/hip_runtime.h>
#include <hip/hip_fp16.h>

typedef _Float16 v2h __attribute__((ext_vector_type(2)));
typedef _Float16 h4t __attribute__((ext_vector_type(4)));
typedef _Float16 h8t __attribute__((ext_vector_type(8)));
typedef float f4t __attribute__((ext_vector_type(4)));

static constexpr int T = 512;
static constexpr int B = 4096;

// prescale constants: sigmoid gates get -log2e, tanh gates get -2*log2e
static constexpr float SG = -1.4426950408889634f;
static constexpr float SN = -2.8853900817779268f;

__device__ __forceinline__ float frcp_(float x) { return __builtin_amdgcn_rcpf(x); }
__device__ __forceinline__ float exp2_(float x) {
#if __has_builtin(__builtin_amdgcn_exp2f)
    return __builtin_amdgcn_exp2f(x);
#else
    return __expf(x * 0.69314718055994531f);
#endif
}
__device__ __forceinline__ float sigp_(float p) { return frcp_(1.0f + exp2_(p)); }
__device__ __forceinline__ float tanhp_(float p) { return fmaf(2.0f, frcp_(1.0f + exp2_(p)), -1.0f); }

#define WAVE_SYNC() do { asm volatile("" ::: "memory"); \
                         __builtin_amdgcn_wave_barrier(); \
                         asm volatile("" ::: "memory"); } while (0)

__device__ __forceinline__ v2h as_h2_(unsigned u) {
    union { unsigned u; v2h h; } c; c.u = u; return c.h;
}

// pack 4 floats -> h4t via two v_cvt_pkrtz
__device__ __forceinline__ h4t pack4_(float a, float b, float c, float d) {
    auto p0 = __builtin_amdgcn_cvt_pkrtz(a, b);
    auto p1 = __builtin_amdgcn_cvt_pkrtz(c, d);
    union { struct { decltype(p0) a, b; } p; h4t h; } cv;
    cv.p.a = p0; cv.p.b = p1;
    return cv.h;
}

// ------- Kernel 1: layer-0 fwd+bwd PAIRED in one 16-lane group -------------
// Group = 16 lanes owns sequence b: unit A = forward, unit B = backward
// (shared x row). The two units' chains interleave in-wave (ILP), hiding
// LDS/trans latency at 1 wave/SIMD. Merged-rcp nonlinearity: 9 trans per
// step-pair (vs 12). Outputs y0f / y0b [T,B,16] f16.
__global__ void __launch_bounds__(256, 1) k_l0p(
    const float* __restrict__ x,
    const float* __restrict__ Wf, const float* __restrict__ Uf,
    const float* __restrict__ bif, const float* __restrict__ bhf,
    const float* __restrict__ Wb, const float* __restrict__ Ub,
    const float* __restrict__ bib, const float* __restrict__ bhb,
    __half* __restrict__ y0f, __half* __restrict__ y0b)
{
    __shared__ __half hbuf[512];      // [0:256) A-slots, [256:512) B-slots
    const int tid = threadIdx.x;
    const int j   = tid & 15;
    const int grp = tid >> 4;         // 0..15
    const int b   = blockIdx.x * 16 + grp;
    __half* hbA = hbuf + grp * 16;
    __half* hbB = hbuf + 256 + grp * 16;

    // A (forward) weights, prescaled f16 pairs
    v2h wrA[8], wzA[8], wnA[8], wrB[8], wzB[8], wnB[8];
#pragma unroll
    for (int q = 0; q < 8; ++q) {
        wrA[q] = (v2h){ (_Float16)(SG * Uf[j * 16 + 2 * q]),
                        (_Float16)(SG * Uf[j * 16 + 2 * q + 1]) };
        wzA[q] = (v2h){ (_Float16)(SG * Uf[(16 + j) * 16 + 2 * q]),
                        (_Float16)(SG * Uf[(16 + j) * 16 + 2 * q + 1]) };
        wnA[q] = (v2h){ (_Float16)(SN * Uf[(32 + j) * 16 + 2 * q]),
                        (_Float16)(SN * Uf[(32 + j) * 16 + 2 * q + 1]) };
        wrB[q] = (v2h){ (_Float16)(SG * Ub[j * 16 + 2 * q]),
                        (_Float16)(SG * Ub[j * 16 + 2 * q + 1]) };
        wzB[q] = (v2h){ (_Float16)(SG * Ub[(16 + j) * 16 + 2 * q]),
                        (_Float16)(SG * Ub[(16 + j) * 16 + 2 * q + 1]) };
        wnB[q] = (v2h){ (_Float16)(SN * Ub[(32 + j) * 16 + 2 * q]),
                        (_Float16)(SN * Ub[(32 + j) * 16 + 2 * q + 1]) };
    }
    const float wxrA = SG * Wf[j], wxzA = SG * Wf[16 + j], wxnA = SN * Wf[32 + j];
    const float brA  = SG * (bif[j] + bhf[j]);
    const float bzA  = SG * (bif[16 + j] + bhf[16 + j]);
    const float binA = SN * bif[32 + j];
    const float bhnA = SN * bhf[32 + j];
    const float wxrB = SG * Wb[j], wxzB = SG * Wb[16 + j], wxnB = SN * Wb[32 + j];
    const float brB  = SG * (bib[j] + bhb[j]);
    const float bzB  = SG * (bib[16 + j] + bhb[16 + j]);
    const float binB = SN * bib[32 + j];
    const float bhnB = SN * bhb[32 + j];

    const float* xrow = x + (size_t)b * T;
    __half* ypA = y0f + (size_t)b * 16 + j;                      // t=0
    __half* ypB = y0b + ((size_t)(T - 1) * B + b) * 16 + j;      // t=T-1
    const ptrdiff_t ystp = (ptrdiff_t)B * 16;

    hbA[j] = __half(0.0f);
    hbB[j] = __half(0.0f);
    WAVE_SYNC();

    float xvA = xrow[0],      x1A = xrow[1];
    float xvB = xrow[T - 1],  x1B = xrow[T - 2];
    const float* xqA = xrow + 2;
    const float* xqB = xrow + T - 3;
    float hA = 0.0f, hB = 0.0f;

    for (int it = 0; it < T; ++it) {
        float x2A = *xqA, x2B = *xqB;
        if (it < T - 3) { xqA += 1; xqB -= 1; }
        const uint4* hpA = reinterpret_cast<const uint4*>(hbA);
        const uint4* hpB = reinterpret_cast<const uint4*>(hbB);
        uint4 a0 = hpA[0], a1 = hpA[1];
        uint4 b0 = hpB[0], b1 = hpB[1];

        float arA = fmaf(xvA, wxrA, brA), azA = fmaf(xvA, wxzA, bzA), hnA = bhnA;
        float arB = fmaf(xvB, wxrB, brB), azB = fmaf(xvB, wxzB, bzB), hnB = bhnB;
        const unsigned ha[8] = { a0.x, a0.y, a0.z, a0.w, a1.x, a1.y, a1.z, a1.w };
        const unsigned hbw[8] = { b0.x, b0.y, b0.z, b0.w, b1.x, b1.y, b1.z, b1.w };
#pragma unroll
        for (int q = 0; q < 8; ++q) {
            v2h hh = as_h2_(ha[q]);
            arA = __builtin_amdgcn_fdot2(hh, wrA[q], arA, false);
            azA = __builtin_amdgcn_fdot2(hh, wzA[q], azA, false);
            hnA = __builtin_amdgcn_fdot2(hh, wnA[q], hnA, false);
            v2h gg = as_h2_(hbw[q]);
            arB = __builtin_amdgcn_fdot2(gg, wrB[q], arB, false);
            azB = __builtin_amdgcn_fdot2(gg, wzB[q], azB, false);
            hnB = __builtin_amdgcn_fdot2(gg, wnB[q], hnB, false);
        }
        // merged-rcp nonlinearity: 6 exp2 + 3 rcp for the pair
        float EaA = exp2_(arA), EzA = exp2_(azA);
        float EaB = exp2_(arB), EzB = exp2_(azB);
        float aA = 1.0f + EaA, bA = 1.0f + EzA;
        float aB = 1.0f + EaB, bB = 1.0f + EzB;
        float invA = frcp_(aA * bA);
        float invB = frcp_(aB * bB);
        float rA = invA * bA, zA = invA * aA;
        float rB = invB * bB, zB = invB * aB;
        float pnA = fmaf(rA, hnA, fmaf(xvA, wxnA, binA));
        float pnB = fmaf(rB, hnB, fmaf(xvB, wxnB, binB));
        float cA = 1.0f + exp2_(pnA);
        float cB = 1.0f + exp2_(pnB);
        float invn = frcp_(cA * cB);
        float nA = fmaf(2.0f * cB, invn, -1.0f);
        float nB = fmaf(2.0f * cA, invn, -1.0f);
        hA = fmaf(zA, hA - nA, nA);
        hB = fmaf(zB, hB - nB, nB);
        __half hfA = __float2half(hA);
        __half hfB = __float2half(hB);
        *ypA = hfA; ypA += ystp;
        *ypB = hfB; ypB -= ystp;
        WAVE_SYNC();                   // reads above the writes
        hbA[j] = hfA;
        hbB[j] = hfB;
        WAVE_SYNC();                   // writes before next-iter reads
        xvA = x1A; x1A = x2A;
        xvB = x1B; x1B = x2B;
    }
}

// ---------------- Kernel 2: layer-1 via MFMA, 16 sequences per wave --------
// r14 base (proven 106 us) + pairwise-rcp merge: 18 trans/step (vs 24).
__global__ void __launch_bounds__(64, 1) k_l1m(
    const __half* __restrict__ y0f, const __half* __restrict__ y0b,
    const float* __restrict__ Wih1, const float* __restrict__ Whh1,
    const float* __restrict__ bih1, const float* __restrict__ bhh1,
    const float* __restrict__ Wih1b,
    const float* __restrict__ bih1b, const float* __restrict__ bhh1b,
    float* __restrict__ out)              // [B,32]
{
    const int lane = threadIdx.x & 63;
    const int c = lane & 15;
    const int g = lane >> 4;
    const int b = blockIdx.x * 16 + c;

    h8t Air, Aiz, Ain;
    {
        const float* pr = Wih1 + (size_t)c * 32 + 8 * g;
        const float* pz = Wih1 + (size_t)(16 + c) * 32 + 8 * g;
        const float* pn = Wih1 + (size_t)(32 + c) * 32 + 8 * g;
#pragma unroll
        for (int e = 0; e < 8; ++e) {
            Air[e] = (_Float16)(SG * pr[e]);
            Aiz[e] = (_Float16)(SG * pz[e]);
            Ain[e] = (_Float16)(SN * pn[e]);
        }
    }
    h4t Ahr, Ahz, Ahn;
    {
        const float* pr = Whh1 + (size_t)c * 16 + 4 * g;
        const float* pz = Whh1 + (size_t)(16 + c) * 16 + 4 * g;
        const float* pn = Whh1 + (size_t)(32 + c) * 16 + 4 * g;
#pragma unroll
        for (int e = 0; e < 4; ++e) {
            Ahr[e] = (_Float16)(SG * pr[e]);
            Ahz[e] = (_Float16)(SG * pz[e]);
            Ahn[e] = (_Float16)(SN * pn[e]);
        }
    }
    f4t Crb, Czb, Cnb, Chn;
#pragma unroll
    for (int i = 0; i < 4; ++i) {
        const int row = 4 * g + i;
        Crb[i] = SG * (bih1[row] + bhh1[row]);
        Czb[i] = SG * (bih1[16 + row] + bhh1[16 + row]);
        Cnb[i] = SN * bih1[32 + row];
        Chn[i] = SN * bhh1[32 + row];
    }

    const __half* ysrc = (g < 2) ? y0f : y0b;
    const uint4* yp = reinterpret_cast<const uint4*>(
        ysrc + (size_t)b * 16 + (size_t)(g & 1) * 8);
    const size_t ystr = (size_t)B * 2;

    uint4 buf[8];
#pragma unroll
    for (int i = 0; i < 8; ++i) buf[i] = yp[(size_t)i * ystr];

    float h[4] = {0.0f, 0.0f, 0.0f, 0.0f};
    h4t Bh = {};

#pragma unroll 8
    for (int it = 0; it < T; ++it) {
        uint4 ya = buf[it & 7];
        const size_t tn = (it + 8 < T) ? (size_t)(it + 8) : (size_t)(T - 1);
        buf[it & 7] = yp[tn * ystr];
        h8t By;
        { union { uint4 u; h8t h; } cv; cv.u = ya; By = cv.h; }
        f4t Dr = __builtin_amdgcn_mfma_f32_16x16x32_f16(Air, By, Crb, 0, 0, 0);
        f4t Dz = __builtin_amdgcn_mfma_f32_16x16x32_f16(Aiz, By, Czb, 0, 0, 0);
        f4t Dn = __builtin_amdgcn_mfma_f32_16x16x32_f16(Ain, By, Cnb, 0, 0, 0);
        f4t Er = __builtin_amdgcn_mfma_f32_16x16x16f16(Ahr, Bh, Dr, 0, 0, 0);  // C-chained
        f4t Ez = __builtin_amdgcn_mfma_f32_16x16x16f16(Ahz, Bh, Dz, 0, 0, 0);  // C-chained
        f4t En = __builtin_amdgcn_mfma_f32_16x16x16f16(Ahn, Bh, Chn, 0, 0, 0);
        // merged-rcp nonlinearity: 12 exp2 + 6 rcp
        float zv[4], cc[4];
#pragma unroll
        for (int i = 0; i < 4; ++i) {
            float Ea = exp2_(Er[i]);
            float Ezv = exp2_(Ez[i]);
            float a = 1.0f + Ea, bb2 = 1.0f + Ezv;
            float inv = frcp_(a * bb2);
            float r = inv * bb2;
            zv[i] = inv * a;
            float pn = fmaf(r, En[i], Dn[i]);
            cc[i] = 1.0f + exp2_(pn);
        }
        float inv01 = frcp_(cc[0] * cc[1]);
        float inv23 = frcp_(cc[2] * cc[3]);
        float n0 = fmaf(2.0f * cc[1], inv01, -1.0f);
        float n1 = fmaf(2.0f * cc[0], inv01, -1.0f);
        float n2 = fmaf(2.0f * cc[3], inv23, -1.0f);
        float n3 = fmaf(2.0f * cc[2], inv23, -1.0f);
        h[0] = fmaf(zv[0], h[0] - n0, n0);
        h[1] = fmaf(zv[1], h[1] - n1, n1);
        h[2] = fmaf(zv[2], h[2] - n2, n2);
        h[3] = fmaf(zv[3], h[3] - n3, n3);
        Bh = pack4_(h[0], h[1], h[2], h[3]);
    }

#pragma unroll
    for (int i = 0; i < 4; ++i)
        out[(size_t)b * 32 + 4 * g + i] = h[i];

    // ---- L1 backward single step at t=T-1 from h=0.
    uint4 yfin = buf[(T - 1) & 7];
    h8t Abr, Abz, Abn;
    {
        const float* pr = Wih1b + (size_t)c * 32 + 8 * g;
        const float* pz = Wih1b + (size_t)(16 + c) * 32 + 8 * g;
        const float* pn = Wih1b + (size_t)(32 + c) * 32 + 8 * g;
#pragma unroll
        for (int e = 0; e < 8; ++e) {
            Abr[e] = (_Float16)(SG * pr[e]);
            Abz[e] = (_Float16)(SG * pz[e]);
            Abn[e] = (_Float16)(SN * pn[e]);
        }
    }
    f4t Cbr, Cbz, Cbn;
    float ghn[4];
#pragma unroll
    for (int i = 0; i < 4; ++i) {
        const int row = 4 * g + i;
        Cbr[i] = SG * (bih1b[row] + bhh1b[row]);
        Cbz[i] = SG * (bih1b[16 + row] + bhh1b[16 + row]);
        Cbn[i] = SN * bih1b[32 + row];
        ghn[i] = SN * bhh1b[32 + row];
    }
    h8t By;
    { union { uint4 u; h8t h; } cv; cv.u = yfin; By = cv.h; }
    f4t Dr = __builtin_amdgcn_mfma_f32_16x16x32_f16(Abr, By, Cbr, 0, 0, 0);
    f4t Dz = __builtin_amdgcn_mfma_f32_16x16x32_f16(Abz, By, Cbz, 0, 0, 0);
    f4t Dn = __builtin_amdgcn_mfma_f32_16x16x32_f16(Abn, By, Cbn, 0, 0, 0);
#pragma unroll
    for (int i = 0; i < 4; ++i) {
        float r = sigp_(Dr[i]);
        float z = sigp_(Dz[i]);
        float n = tanhp_(fmaf(r, ghn[i], Dn[i]));
        out[(size_t)b * 32 + 16 + 4 * g + i] = (1.0f - z) * n;
    }
}

extern "C" void kernel_launch(void* const* d_in, const int* in_sizes, int n_in,
                              void* d_out, int out_size, void* d_ws, size_t ws_size,
                              hipStream_t stream) {
    const float* x     = (const float*)d_in[0];
    const float* Wih0f = (const float*)d_in[1];
    const float* Whh0f = (const float*)d_in[2];
    const float* bih0f = (const float*)d_in[3];
    const float* bhh0f = (const float*)d_in[4];
    const float* Wih0b = (const float*)d_in[5];
    const float* Whh0b = (const float*)d_in[6];
    const float* bih0b = (const float*)d_in[7];
    const float* bhh0b = (const float*)d_in[8];
    const float* Wih1f = (const float*)d_in[9];
    const float* Whh1f = (const float*)d_in[10];
    const float* bih1f = (const float*)d_in[11];
    const float* bhh1f = (const float*)d_in[12];
    const float* Wih1b = (const float*)d_in[13];
    const float* bih1b = (const float*)d_in[15];
    const float* bhh1b = (const float*)d_in[16];

    __half* y0f = (__half*)d_ws;                   // [T,B,16] f16 = 64 MiB
    __half* y0b = y0f + (size_t)T * B * 16;        // [T,B,16] f16 = 64 MiB
    float* out = (float*)d_out;

    // K1: 4096 seqs (fwd+bwd paired), 16 per block -> 256 blocks (1024 waves).
    hipLaunchKernelGGL(k_l0p, dim3(B / 16), dim3(256), 0, stream,
                       x, Wih0f, Whh0f, bih0f, bhh0f,
                       Wih0b, Whh0b, bih0b, bhh0b, y0f, y0b);
    // K2: 4096 seqs, 16 per wave -> 256 blocks.
    hipLaunchKernelGGL(k_l1m, dim3(B / 16), dim3(64), 0, stream,
                       y0f, y0b, Wih1f, Whh1f, bih1f, bhh1f,
                       Wih1b, bih1b, bhh1b, out);
}

// Round 17
// 249.660 us; speedup vs baseline: 1.2946x; 1.2257x over previous
//
#include <hip/hip_runtime.h>
#include <hip/hip_fp16.h>

typedef _Float16 v2h __attribute__((ext_vector_type(2)));
typedef _Float16 h4t __attribute__((ext_vector_type(4)));
typedef _Float16 h8t __attribute__((ext_vector_type(8)));
typedef float f4t __attribute__((ext_vector_type(4)));

static constexpr int T = 512;
static constexpr int B = 4096;

// prescale constants: sigmoid gates get -log2e, tanh gates get -2*log2e
static constexpr float SG = -1.4426950408889634f;
static constexpr float SN = -2.8853900817779268f;

__device__ __forceinline__ float frcp_(float x) { return __builtin_amdgcn_rcpf(x); }
__device__ __forceinline__ float exp2_(float x) {
#if __has_builtin(__builtin_amdgcn_exp2f)
    return __builtin_amdgcn_exp2f(x);
#else
    return __expf(x * 0.69314718055994531f);
#endif
}
__device__ __forceinline__ float sigp_(float p) { return frcp_(1.0f + exp2_(p)); }
__device__ __forceinline__ float tanhp_(float p) { return fmaf(2.0f, frcp_(1.0f + exp2_(p)), -1.0f); }

#define WAVE_SYNC() do { asm volatile("" ::: "memory"); \
                         __builtin_amdgcn_wave_barrier(); \
                         asm volatile("" ::: "memory"); } while (0)

__device__ __forceinline__ v2h as_h2_(unsigned u) {
    union { unsigned u; v2h h; } c; c.u = u; return c.h;
}

// pack 4 floats -> h4t via two v_cvt_pkrtz
__device__ __forceinline__ h4t pack4_(float a, float b, float c, float d) {
    auto p0 = __builtin_amdgcn_cvt_pkrtz(a, b);
    auto p1 = __builtin_amdgcn_cvt_pkrtz(c, d);
    union { struct { decltype(p0) a, b; } p; h4t h; } cv;
    cv.p.a = p0; cv.p.b = p1;
    return cv.h;
}

// ---------------- Kernel 1: layer-0 forward AND backward scans -------------
// r14 structure (proven 143 us): tid = [s:3][dir:1][j:4]; 16-lane unit per
// (seq,dir); f16 LDS h-exchange; fdot2 gate dots with exp2-prescaled f16
// weights. This round: merged r/z rcp (5 trans/wave-step vs 6).
__global__ void __launch_bounds__(256, 2) k_l0(
    const float* __restrict__ x,      // [B,T]
    const float* __restrict__ Wf, const float* __restrict__ Uf,
    const float* __restrict__ bif, const float* __restrict__ bhf,
    const float* __restrict__ Wb, const float* __restrict__ Ub,
    const float* __restrict__ bib, const float* __restrict__ bhb,
    __half* __restrict__ y0f,         // [T,B,16] f16
    __half* __restrict__ y0b)         // [T,B,16] f16
{
    __shared__ __half hbuf[256];      // 16 units x 16 f16 (32 B/unit)
    const int tid  = threadIdx.x;
    const int j    = tid & 15;
    const int dir  = (tid >> 4) & 1;
    const int s    = tid >> 5;
    const int unit = tid >> 4;
    const int b    = blockIdx.x * 8 + s;
    __half* hb = hbuf + unit * 16;

    const float* Wih = dir ? Wb : Wf;
    const float* Whh = dir ? Ub : Uf;
    const float* bih = dir ? bib : bif;
    const float* bhh = dir ? bhb : bhf;

    v2h wr[8], wz[8], wn[8];
#pragma unroll
    for (int q = 0; q < 8; ++q) {
        wr[q] = (v2h){ (_Float16)(SG * Whh[j * 16 + 2 * q]),
                       (_Float16)(SG * Whh[j * 16 + 2 * q + 1]) };
        wz[q] = (v2h){ (_Float16)(SG * Whh[(16 + j) * 16 + 2 * q]),
                       (_Float16)(SG * Whh[(16 + j) * 16 + 2 * q + 1]) };
        wn[q] = (v2h){ (_Float16)(SN * Whh[(32 + j) * 16 + 2 * q]),
                       (_Float16)(SN * Whh[(32 + j) * 16 + 2 * q + 1]) };
    }
    const float wxr  = SG * Wih[j], wxz = SG * Wih[16 + j], wxn = SN * Wih[32 + j];
    const float br   = SG * (bih[j] + bhh[j]);
    const float bz   = SG * (bih[16 + j] + bhh[16 + j]);
    const float bin_ = SN * bih[32 + j];
    const float bhn  = SN * bhh[32 + j];

    const int t0   = dir ? (T - 1) : 0;
    const int step = dir ? -1 : 1;
    const float* xp = x + (size_t)b * T + t0;
    __half* yp = (dir ? y0b : y0f) + ((size_t)t0 * B + b) * 16 + j;
    const ptrdiff_t ystep = (ptrdiff_t)step * B * 16;

    hb[j] = __half(0.0f);
    WAVE_SYNC();

    float xv = xp[0];
    float x1 = xp[step];
    const float* xq = xp + 2 * step;   // 2-deep prefetch
    float hj = 0.0f;

    for (int it = 0; it < T; ++it) {
        float x2 = *xq;
        if (it < T - 3) xq += step;
        const uint4* hp = reinterpret_cast<const uint4*>(hb);
        uint4 u0 = hp[0], u1 = hp[1];
        float ar = fmaf(xv, wxr, br);
        float az = fmaf(xv, wxz, bz);
        float hn = bhn;
        const unsigned hw[8] = { u0.x, u0.y, u0.z, u0.w, u1.x, u1.y, u1.z, u1.w };
#pragma unroll
        for (int q = 0; q < 8; ++q) {
            v2h hh = as_h2_(hw[q]);
            ar = __builtin_amdgcn_fdot2(hh, wr[q], ar, false);
            az = __builtin_amdgcn_fdot2(hh, wz[q], az, false);
            hn = __builtin_amdgcn_fdot2(hh, wn[q], hn, false);
        }
        // merged r/z rcp: 2 exp2 + 1 rcp (tanh keeps its own exp2+rcp)
        float Ea = exp2_(ar), Ez = exp2_(az);
        float a2 = 1.0f + Ea, b2 = 1.0f + Ez;
        float inv = frcp_(a2 * b2);
        float r = inv * b2, z = inv * a2;
        float n = tanhp_(fmaf(r, hn, fmaf(xv, wxn, bin_)));
        hj = fmaf(z, hj - n, n);            // (1-z)*n + z*h
        __half hf = __float2half(hj);
        *yp = hf;
        yp += ystep;
        WAVE_SYNC();
        hb[j] = hf;
        WAVE_SYNC();
        xv = x1; x1 = x2;
    }
}

// ---------------- Kernel 2: layer-1 via MFMA, 16 sequences per wave --------
// r14 version verbatim (proven ~107 us): exp2 prefolding + C-chaining,
// 8-deep rotating y prefetch, no LDS.
__global__ void __launch_bounds__(64, 1) k_l1m(
    const __half* __restrict__ y0f, const __half* __restrict__ y0b,
    const float* __restrict__ Wih1, const float* __restrict__ Whh1,
    const float* __restrict__ bih1, const float* __restrict__ bhh1,
    const float* __restrict__ Wih1b,
    const float* __restrict__ bih1b, const float* __restrict__ bhh1b,
    float* __restrict__ out)              // [B,32]
{
    const int lane = threadIdx.x & 63;
    const int c = lane & 15;
    const int g = lane >> 4;
    const int b = blockIdx.x * 16 + c;

    h8t Air, Aiz, Ain;
    {
        const float* pr = Wih1 + (size_t)c * 32 + 8 * g;
        const float* pz = Wih1 + (size_t)(16 + c) * 32 + 8 * g;
        const float* pn = Wih1 + (size_t)(32 + c) * 32 + 8 * g;
#pragma unroll
        for (int e = 0; e < 8; ++e) {
            Air[e] = (_Float16)(SG * pr[e]);
            Aiz[e] = (_Float16)(SG * pz[e]);
            Ain[e] = (_Float16)(SN * pn[e]);
        }
    }
    h4t Ahr, Ahz, Ahn;
    {
        const float* pr = Whh1 + (size_t)c * 16 + 4 * g;
        const float* pz = Whh1 + (size_t)(16 + c) * 16 + 4 * g;
        const float* pn = Whh1 + (size_t)(32 + c) * 16 + 4 * g;
#pragma unroll
        for (int e = 0; e < 4; ++e) {
            Ahr[e] = (_Float16)(SG * pr[e]);
            Ahz[e] = (_Float16)(SG * pz[e]);
            Ahn[e] = (_Float16)(SN * pn[e]);
        }
    }
    f4t Crb, Czb, Cnb, Chn;
#pragma unroll
    for (int i = 0; i < 4; ++i) {
        const int row = 4 * g + i;
        Crb[i] = SG * (bih1[row] + bhh1[row]);
        Czb[i] = SG * (bih1[16 + row] + bhh1[16 + row]);
        Cnb[i] = SN * bih1[32 + row];
        Chn[i] = SN * bhh1[32 + row];
    }

    const __half* ysrc = (g < 2) ? y0f : y0b;
    const uint4* yp = reinterpret_cast<const uint4*>(
        ysrc + (size_t)b * 16 + (size_t)(g & 1) * 8);
    const size_t ystr = (size_t)B * 2;            // uint4 per time step

    uint4 buf[8];
#pragma unroll
    for (int i = 0; i < 8; ++i) buf[i] = yp[(size_t)i * ystr];

    float h[4] = {0.0f, 0.0f, 0.0f, 0.0f};
    h4t Bh = {};

#pragma unroll 8
    for (int it = 0; it < T; ++it) {
        uint4 ya = buf[it & 7];
        const size_t tn = (it + 8 < T) ? (size_t)(it + 8) : (size_t)(T - 1);
        buf[it & 7] = yp[tn * ystr];              // issue load for t+8
        h8t By;
        { union { uint4 u; h8t h; } cv; cv.u = ya; By = cv.h; }
        f4t Dr = __builtin_amdgcn_mfma_f32_16x16x32_f16(Air, By, Crb, 0, 0, 0);
        f4t Dz = __builtin_amdgcn_mfma_f32_16x16x32_f16(Aiz, By, Czb, 0, 0, 0);
        f4t Dn = __builtin_amdgcn_mfma_f32_16x16x32_f16(Ain, By, Cnb, 0, 0, 0);
        f4t Er = __builtin_amdgcn_mfma_f32_16x16x16f16(Ahr, Bh, Dr, 0, 0, 0);  // C-chained
        f4t Ez = __builtin_amdgcn_mfma_f32_16x16x16f16(Ahz, Bh, Dz, 0, 0, 0);  // C-chained
        f4t En = __builtin_amdgcn_mfma_f32_16x16x16f16(Ahn, Bh, Chn, 0, 0, 0);
#pragma unroll
        for (int i = 0; i < 4; ++i) {
            float r = sigp_(Er[i]);
            float z = sigp_(Ez[i]);
            float n = tanhp_(fmaf(r, En[i], Dn[i]));
            h[i] = fmaf(z, h[i] - n, n);
        }
        Bh = pack4_(h[0], h[1], h[2], h[3]);
    }

#pragma unroll
    for (int i = 0; i < 4; ++i)
        out[(size_t)b * 32 + 4 * g + i] = h[i];

    // ---- L1 backward single step at t=T-1 from h=0.
    uint4 yfin = buf[(T - 1) & 7];
    h8t Abr, Abz, Abn;
    {
        const float* pr = Wih1b + (size_t)c * 32 + 8 * g;
        const float* pz = Wih1b + (size_t)(16 + c) * 32 + 8 * g;
        const float* pn = Wih1b + (size_t)(32 + c) * 32 + 8 * g;
#pragma unroll
        for (int e = 0; e < 8; ++e) {
            Abr[e] = (_Float16)(SG * pr[e]);
            Abz[e] = (_Float16)(SG * pz[e]);
            Abn[e] = (_Float16)(SN * pn[e]);
        }
    }
    f4t Cbr, Cbz, Cbn;
    float ghn[4];
#pragma unroll
    for (int i = 0; i < 4; ++i) {
        const int row = 4 * g + i;
        Cbr[i] = SG * (bih1b[row] + bhh1b[row]);
        Cbz[i] = SG * (bih1b[16 + row] + bhh1b[16 + row]);
        Cbn[i] = SN * bih1b[32 + row];
        ghn[i] = SN * bhh1b[32 + row];
    }
    h8t By;
    { union { uint4 u; h8t h; } cv; cv.u = yfin; By = cv.h; }
    f4t Dr = __builtin_amdgcn_mfma_f32_16x16x32_f16(Abr, By, Cbr, 0, 0, 0);
    f4t Dz = __builtin_amdgcn_mfma_f32_16x16x32_f16(Abz, By, Cbz, 0, 0, 0);
    f4t Dn = __builtin_amdgcn_mfma_f32_16x16x32_f16(Abn, By, Cbn, 0, 0, 0);
#pragma unroll
    for (int i = 0; i < 4; ++i) {
        float r = sigp_(Dr[i]);
        float z = sigp_(Dz[i]);
        float n = tanhp_(fmaf(r, ghn[i], Dn[i]));
        out[(size_t)b * 32 + 16 + 4 * g + i] = (1.0f - z) * n;
    }
}

extern "C" void kernel_launch(void* const* d_in, const int* in_sizes, int n_in,
                              void* d_out, int out_size, void* d_ws, size_t ws_size,
                              hipStream_t stream) {
    const float* x     = (const float*)d_in[0];
    const float* Wih0f = (const float*)d_in[1];
    const float* Whh0f = (const float*)d_in[2];
    const float* bih0f = (const float*)d_in[3];
    const float* bhh0f = (const float*)d_in[4];
    const float* Wih0b = (const float*)d_in[5];
    const float* Whh0b = (const float*)d_in[6];
    const float* bih0b = (const float*)d_in[7];
    const float* bhh0b = (const float*)d_in[8];
    const float* Wih1f = (const float*)d_in[9];
    const float* Whh1f = (const float*)d_in[10];
    const float* bih1f = (const float*)d_in[11];
    const float* bhh1f = (const float*)d_in[12];
    const float* Wih1b = (const float*)d_in[13];
    const float* bih1b = (const float*)d_in[15];
    const float* bhh1b = (const float*)d_in[16];

    __half* y0f = (__half*)d_ws;                   // [T,B,16] f16 = 64 MiB
    __half* y0b = y0f + (size_t)T * B * 16;        // [T,B,16] f16 = 64 MiB
    float* out = (float*)d_out;

    // K1: 8192 (seq,dir) units, 16 units/block -> 512 blocks (2048 waves).
    hipLaunchKernelGGL(k_l0, dim3(B * 2 / 16), dim3(256), 0, stream,
                       x, Wih0f, Whh0f, bih0f, bhh0f,
                       Wih0b, Whh0b, bih0b, bhh0b, y0f, y0b);
    // K2: 4096 seqs, 16 per wave -> 256 blocks.
    hipLaunchKernelGGL(k_l1m, dim3(B / 16), dim3(64), 0, stream,
                       y0f, y0b, Wih1f, Whh1f, bih1f, bhh1f,
                       Wih1b, bih1b, bhh1b, out);
}